// Round 3
// baseline (365.517 us; speedup 1.0000x reference)
//
#include <hip/hip_runtime.h>
#include <math.h>

#define NQ 20
#define NL 4

// Quantum circuit sim, N=20 qubits, 4 layers, batch 16. State purely real -> f32.
// qubit q <-> bit (19-q). Per layer:
//   hpass: RY(0..5) + CNOT(0,1)..(4,5)    bits 19..14, 64 float2/thread (128 regs)
//   tpass: RY(6..19) + CNOT(5,6)..(18,19) bits 13..0, 2^14-chunk (64 KiB LDS,
//          2 blocks/CU), 512 thr x 32 elems, rounds A=bits[13:9], B=bits[8:4],
//          C=bits[4:0]; XOR swizzle keeps all LDS phases <=2-way (free).

__global__ void cs_kernel(const float* theta, float* cs) {
    int i = threadIdx.x;
    if (i < NL * NQ) {
        float s, c;
        sincosf(theta[i] * 0.5f, &s, &c);
        cs[2 * i]     = c;
        cs[2 * i + 1] = s;
    }
}

__global__ __launch_bounds__(256, 2) void hpass_kernel(
    const float* in, float* out, const float* cs, int layer)
{
    int g = blockIdx.x * 256 + threadIdx.x;      // 0..131071 (16 * 2^13)
    int b = g >> 13;                             // batch
    int r = g & 8191;                            // j bits [13:1]
    const float2* src = (const float2*)(in + ((size_t)b << 20)) + r;
    float2*       dst = (float2*)(out + ((size_t)b << 20)) + r;
    const float2* cst = (const float2*)cs + layer * NQ;

    float2 v[64];                                // h = j bits [19:14]
#pragma unroll
    for (int h = 0; h < 64; ++h) v[h] = src[h * 8192];

    // RY q=0..5: h-bit (5-q)
#pragma unroll
    for (int q = 0; q < 6; ++q) {
        float2 sc = cst[q];
        float c = sc.x, s = sc.y;
        int mask = 1 << (5 - q);
#pragma unroll
        for (int h = 0; h < 64; ++h) {
            if (!(h & mask)) {
                float2 a = v[h], bb = v[h | mask];
                v[h].x        = c * a.x - s * bb.x;
                v[h].y        = c * a.y - s * bb.y;
                v[h | mask].x = s * a.x + c * bb.x;
                v[h | mask].y = s * a.y + c * bb.y;
            }
        }
    }
    // CNOT(q,q+1) q=0..4: ctrl h-bit(5-q), target h-bit(4-q) -> register rename
#pragma unroll
    for (int q = 0; q < 5; ++q) {
        int cm = 1 << (5 - q), tm = 1 << (4 - q);
#pragma unroll
        for (int h = 0; h < 64; ++h) {
            if ((h & cm) && !(h & tm)) {
                float2 tmp = v[h]; v[h] = v[h | tm]; v[h | tm] = tmp;
            }
        }
    }

#pragma unroll
    for (int h = 0; h < 64; ++h) dst[h * 8192] = v[h];
}

template <bool DO_ABS>
__global__ __launch_bounds__(512) void tpass_kernel(
    float* st, const float* cs, int layer)
{
    __shared__ float lds[16384];                 // 64 KiB -> 2 blocks/CU
    int t   = threadIdx.x;                       // 0..511
    int blk = blockIdx.x;                        // 0..1023
    int ci  = blk & 63;                          // j bits [19:14]
    int b   = blk >> 6;
    float* g = st + ((size_t)b << 20) + ((size_t)ci << 14);
    const float2* cst = (const float2*)cs + layer * NQ;

    float v[32];

    // ---- Round A: m = bits[13:9] (q6..10); thread = bits[8:0] ----
#pragma unroll
    for (int m = 0; m < 32; ++m) v[m] = g[m * 512 + t];

#pragma unroll
    for (int i = 0; i < 5; ++i) {                // RY q=6+i, m-bit (4-i)
        float2 sc = cst[6 + i];
        float c = sc.x, s = sc.y;
        int mask = 16 >> i;
#pragma unroll
        for (int m = 0; m < 32; ++m) {
            if (!(m & mask)) {
                float a = v[m], bb = v[m | mask];
                v[m]        = c * a - s * bb;
                v[m | mask] = s * a + c * bb;
            }
        }
    }
    // CNOT(5,6): ctrl bit14 = ci&1 (block-uniform), target m-bit 4
    if (ci & 1) {
#pragma unroll
        for (int m = 0; m < 16; ++m) { float tmp = v[m]; v[m] = v[m | 16]; v[m | 16] = tmp; }
    }
    // CNOT(6,7)..(9,10): ctrl m-bit(4-i), target m-bit(3-i)
#pragma unroll
    for (int i = 0; i < 4; ++i) {
        int cm = 16 >> i, tm = 8 >> i;
#pragma unroll
        for (int m = 0; m < 32; ++m) {
            if ((m & cm) && !(m & tm)) {
                float tmp = v[m]; v[m] = v[m | tm]; v[m | tm] = tmp;
            }
        }
    }
    // A-write: addr(j) = m*512 + ((j&511) ^ sigma(m) ^ ((j>>5)&15))
    int tw = t ^ (t >> 5);
#pragma unroll
    for (int m = 0; m < 32; ++m) {
        int sig = ((m & 1) << 4) | ((m >> 1) & 15);
        lds[m * 512 + (tw ^ sig)] = v[m];
    }
    __syncthreads();

    // ---- Round B: k = bits[8:4] (q11..15); thread = (m=t>>4, lo=t&15) ----
    int mB = t >> 4, lo = t & 15;
    int sB = ((mB & 1) << 4) | ((mB >> 1) & 15);
    int baseB = mB * 512;
#pragma unroll
    for (int k = 0; k < 32; ++k)
        v[k] = lds[baseB + ((k * 16 + lo) ^ sB ^ (k >> 1))];

#pragma unroll
    for (int i = 0; i < 5; ++i) {                // RY q=11+i, k-bit (4-i)
        float2 sc = cst[11 + i];
        float c = sc.x, s = sc.y;
        int mask = 16 >> i;
#pragma unroll
        for (int k = 0; k < 32; ++k) {
            if (!(k & mask)) {
                float a = v[k], bb = v[k | mask];
                v[k]        = c * a - s * bb;
                v[k | mask] = s * a + c * bb;
            }
        }
    }
    // CNOT(10,11): ctrl bit9 = mB&1 (= t&16), target k-bit 4
    if (t & 16) {
#pragma unroll
        for (int k = 0; k < 16; ++k) { float tmp = v[k]; v[k] = v[k | 16]; v[k | 16] = tmp; }
    }
    // CNOT(11,12)..(14,15): ctrl k-bit(4-i), target k-bit(3-i)
#pragma unroll
    for (int i = 0; i < 4; ++i) {
        int cm = 16 >> i, tm = 8 >> i;
#pragma unroll
        for (int k = 0; k < 32; ++k) {
            if ((k & cm) && !(k & tm)) {
                float tmp = v[k]; v[k] = v[k | tm]; v[k | tm] = tmp;
            }
        }
    }
    // B-write: same thread-owned addresses (no cross-thread hazard)
#pragma unroll
    for (int k = 0; k < 32; ++k)
        lds[baseB + ((k * 16 + lo) ^ sB ^ (k >> 1))] = v[k];
    __syncthreads();

    // ---- Round C: p = bits[4:0] (q15 passive + q16..19); thread = bits[13:5] ----
    int mC = t >> 4, kh = t & 15;
    int sw = (((mC & 1) << 4) | ((mC >> 1) & 15)) ^ kh;
    int baseC = mC * 512 + 0;
#pragma unroll
    for (int p = 0; p < 32; ++p)
        v[p] = lds[baseC + ((kh * 32 + p) ^ sw)];

#pragma unroll
    for (int i = 0; i < 4; ++i) {                // RY q=16+i, p-bit (3-i)
        float2 sc = cst[16 + i];
        float c = sc.x, s = sc.y;
        int mask = 8 >> i;
#pragma unroll
        for (int p = 0; p < 32; ++p) {
            if (!(p & mask)) {
                float a = v[p], bb = v[p | mask];
                v[p]        = c * a - s * bb;
                v[p | mask] = s * a + c * bb;
            }
        }
    }
    // CNOT(15,16): ctrl p-bit 4 (held), target p-bit 3 -> register rename
#pragma unroll
    for (int p = 0; p < 32; ++p) {
        if ((p & 16) && !(p & 8)) { float tmp = v[p]; v[p] = v[p | 8]; v[p | 8] = tmp; }
    }
    // CNOT(16,17)..(18,19): ctrl p-bit(3-i), target p-bit(2-i)
#pragma unroll
    for (int i = 0; i < 3; ++i) {
        int cm = 8 >> i, tm = 4 >> i;
#pragma unroll
        for (int p = 0; p < 32; ++p) {
            if ((p & cm) && !(p & tm)) {
                float tmp = v[p]; v[p] = v[p | tm]; v[p | tm] = tmp;
            }
        }
    }

    // store: thread owns 32 contiguous floats at g + t*32 -> 8x float4
    float4* dst = (float4*)(g + t * 32);
#pragma unroll
    for (int i = 0; i < 8; ++i) {
        float4 w;
        w.x = v[4 * i + 0]; w.y = v[4 * i + 1];
        w.z = v[4 * i + 2]; w.w = v[4 * i + 3];
        if (DO_ABS) {
            w.x = fabsf(w.x); w.y = fabsf(w.y);
            w.z = fabsf(w.z); w.w = fabsf(w.w);
        }
        dst[i] = w;
    }
}

extern "C" void kernel_launch(void* const* d_in, const int* in_sizes, int n_in,
                              void* d_out, int out_size, void* d_ws, size_t ws_size,
                              hipStream_t stream) {
    const float* x     = (const float*)d_in[0];   // (16, 2^20) f32
    const float* theta = (const float*)d_in[1];   // (80,) f32
    float* st = (float*)d_out;                    // state lives in d_out
    float* cs = (float*)d_ws;                     // 80 (cos,sin) pairs

    cs_kernel<<<1, 128, 0, stream>>>(theta, cs);

    for (int l = 0; l < 4; ++l) {
        hpass_kernel<<<512, 256, 0, stream>>>(l == 0 ? x : st, st, cs, l);
        if (l < 3)
            tpass_kernel<false><<<1024, 512, 0, stream>>>(st, cs, l);
        else
            tpass_kernel<true><<<1024, 512, 0, stream>>>(st, cs, l);
    }
}

// Round 4
// 281.632 us; speedup vs baseline: 1.2979x; 1.2979x over previous
//
#include <hip/hip_runtime.h>
#include <math.h>

// Quantum circuit sim, 20 qubits, 4 layers, batch 16, purely-real f32 state.
// Element bit Ek <-> qubit q = 19-k. 7 fused passes, each pass = one kernel:
//   R : RY on E13..E0                       (layer 0)           std -> M
//   A : RY E19..E14(+E13..E6 if FULL) + CNOT chain (19,18)..(7,6)   M -> P
//   F : chain (6,5)..(1,0) [layer l] (+RY E5..E0 if LOWRY)
//       + RY E19..E13 + chain (19,18)..(14,13) [layer l+1]          P -> Q
//   L : RY E12..E0 + chain (13,12)..(1,0) (+abs if FIN)             Q -> M/std
// Schedule: R(0) A(0) F(0,1) L(1) A*(2) F*(2,3) L*(3).
// M/P/Q are bit-permuted inter-pass layouts making every global access a
// dense float4 (16B/lane, full 128B lines per instruction). LDS transposes
// use per-pass XOR-linear swizzles verified <=2-way on every phase.

__global__ void cs_kernel(const float* __restrict__ theta, float2* __restrict__ cs) {
    int i = threadIdx.x;
    if (i < 80) {
        float s, c;
        sincosf(theta[i] * 0.5f, &s, &c);
        cs[i] = make_float2(c, s);
    }
}

// RY on fragment bit MASK with angle table TBL[Q]
#define RYT_(TBL, MASK, Q) { float2 _sc = (TBL)[(Q)]; float _c = _sc.x, _s = _sc.y; \
  _Pragma("unroll") for (int _m = 0; _m < 32; ++_m) if (!(_m & (MASK))) { \
    float _a = v[_m], _b = v[_m | (MASK)]; \
    v[_m] = _c*_a - _s*_b; v[_m | (MASK)] = _s*_a + _c*_b; } }

// CNOT: control mask CM, target mask TM, both in fragment
#define CX_(CM, TM) { _Pragma("unroll") for (int _m = 0; _m < 32; ++_m) \
  if ((_m & (CM)) && !(_m & (TM))) { float _t = v[_m]; v[_m] = v[_m|(TM)]; v[_m|(TM)] = _t; } }

// CNOT with control on a thread-index bit (COND), target mask TM in fragment
#define CXI_(COND, TM) { if (COND) { _Pragma("unroll") for (int _m = 0; _m < 32; ++_m) \
  if (!(_m & (TM))) { float _t = v[_m]; v[_m] = v[_m|(TM)]; v[_m|(TM)] = _t; } } }

__device__ __forceinline__ int mixR(int n) {
    return ((n >> 5) & 31) ^ ((n >> 10) & 1);
}
__device__ __forceinline__ int mixA(int n) {
    return ((n >> 5) & 31) ^ ((n >> 10) & 1) ^ (((n >> 11) & 1) << 3)
         ^ (((n >> 12) & 1) << 4) ^ (((n >> 13) & 1) << 4);
}
__device__ __forceinline__ int mixF(int n) {
    return ((n >> 5) & 31) ^ (((n >> 10) & 1) << 1) ^ (((n >> 11) & 1) << 2)
         ^ (((n >> 12) & 1) << 3) ^ (((n >> 13) & 1) << 4);
}
__device__ __forceinline__ int mixL(int n) {
    return ((n >> 5) & 31) ^ (((n >> 10) & 1) << 4) ^ (((n >> 11) & 1) << 2)
         ^ (((n >> 12) & 1) << 3) ^ (((n >> 13) & 1) << 4);
}

// ---------------- Pass R: std -> M, RY on E13..E0 (layer 0) ----------------
// n: [n0..n4]=(E0,E1,E10,E11,E12) [n5..n10]=(E2..E7) [n11..n13]=(E8,E9,E13)
__global__ __launch_bounds__(512, 4) void pass_R(
    const float4* __restrict__ src, float4* __restrict__ dst,
    const float2* __restrict__ cs)
{
    __shared__ float lds[16384];
    const float2* csl = cs;                       // layer 0
    int t = threadIdx.x, blk = blockIdx.x;
    int H = blk & 63, b = blk >> 6;
    int base = (b << 18) + (H << 12);
    float v[32];

    // load (standard): t[5:0]=E2..E7, t[7:6]=E8,E9, t[8]=E13; i=(E10,E11,E12)
#pragma unroll
    for (int i = 0; i < 8; ++i) {
        float4 w = src[base + (i << 8) + (((t >> 6) & 3) << 6) + (((t >> 8) & 1) << 11) + (t & 63)];
        v[i*4+0] = w.x; v[i*4+1] = w.y; v[i*4+2] = w.z; v[i*4+3] = w.w;
    }
    // r1: m=(E0,E1,E10,E11,E12) -> RY q19,q18,q9,q8,q7
    RYT_(csl, 1, 19); RYT_(csl, 2, 18); RYT_(csl, 4, 9); RYT_(csl, 8, 8); RYT_(csl, 16, 7);
    { int w1x = (t & 31) ^ ((t >> 5) & 1);
#pragma unroll
      for (int m = 0; m < 32; ++m) lds[(t << 5) | (m ^ w1x)] = v[m]; }
    __syncthreads();

    // r2: frag=(E2,E3,E4,E5,E6) -> RY q17,q16,q15,q14,q13
    { int tp = (t & 31) | (((t >> 5) & 1) << 10) | (((t >> 6) & 7) << 11);
      int mt = mixR(tp);
#pragma unroll
      for (int f = 0; f < 32; ++f) { int fc = f << 5; v[f] = lds[(tp | fc) ^ mt ^ mixR(fc)]; }
      RYT_(csl, 1, 17); RYT_(csl, 2, 16); RYT_(csl, 4, 15); RYT_(csl, 8, 14); RYT_(csl, 16, 13);
#pragma unroll
      for (int f = 0; f < 32; ++f) { int fc = f << 5; lds[(tp | fc) ^ mt ^ mixR(fc)] = v[f]; } }
    __syncthreads();

    // r3: p=(E6,E7,E8,E9,E13) -> RY q12(2),q11(4),q10(8),q6(16)
    { int tp = ((t & 1) << 2) | (((t >> 1) & 1) << 3) | (((t >> 2) & 1) << 4)
             | (((t >> 3) & 1) << 5) | (((t >> 4) & 1) << 1) | (((t >> 5) & 1) << 0)
             | (((t >> 6) & 7) << 6);
      int mt = mixR(tp);
#pragma unroll
      for (int p = 0; p < 32; ++p) { int fc = p << 9; v[p] = lds[(tp | fc) ^ mt ^ mixR(fc)]; }
      RYT_(csl, 2, 12); RYT_(csl, 4, 11); RYT_(csl, 8, 10); RYT_(csl, 16, 6);
      // store -> M: f4 = base | j<<9 | t[8:6]<<6 | t[5:0]
      int sb = base + (((t >> 6) & 7) << 6) + (t & 63);
#pragma unroll
      for (int j = 0; j < 8; ++j)
        dst[sb + (j << 9)] = make_float4(v[4*j], v[4*j+1], v[4*j+2], v[4*j+3]); }
}

// ---------------- Pass A: M -> P ----------------
// n: [n0..n4]=(E6,E7,E17,E18,E19) [n5..n10]=(E10,E11,E12,E14,E15,E16)
//    [n11..n13]=(E8,E9,E13)
template <bool FULL>
__global__ __launch_bounds__(512, 4) void pass_A(
    const float4* __restrict__ src, float4* __restrict__ dst,
    const float2* __restrict__ cs, int layer)
{
    __shared__ float lds[16384];
    const float2* csl = cs + layer * 20;
    int t = threadIdx.x, blk = blockIdx.x;
    int G = blk & 63, b = blk >> 6;
    int Gperm = ((G >> 2) & 1) | (((G >> 1) & 1) << 1) | ((G & 1) << 2) | (((G >> 3) & 7) << 3);
    float v[32];

    // load from M
    { int lb = (b << 18) + (((t >> 6) & 7) << 9) + (Gperm << 3) + (t & 7);
      int rg = ((t >> 3) & 7) << 12;
#pragma unroll
      for (int i = 0; i < 8; ++i) {
        float4 w = src[lb + ((i << 3) << 12) + rg];
        v[i*4+0] = w.x; v[i*4+1] = w.y; v[i*4+2] = w.z; v[i*4+3] = w.w;
      } }
    // r1: m=(E6,E7,E17,E18,E19): RY q0(16),q1(8),q2(4); FULL: q12(2),q13(1)
    RYT_(csl, 16, 0); RYT_(csl, 8, 1); RYT_(csl, 4, 2);
    if (FULL) { RYT_(csl, 2, 12); RYT_(csl, 1, 13); }
    { int w1x = (t & 31) ^ ((t >> 5) & 1) ^ (((t >> 6) & 1) << 3)
              ^ (((t >> 7) & 1) << 4) ^ (((t >> 8) & 1) << 4);
#pragma unroll
      for (int m = 0; m < 32; ++m) lds[(t << 5) | (m ^ w1x)] = v[m]; }
    __syncthreads();

    // r2: frag=(E15,E16,E17,E18,E19): RY q4(1),q3(2); links (19,18)..(16,15)
    { int tp = (t & 3) | (((t >> 2) & 1) << 7) | (((t >> 3) & 1) << 11)
             | (((t >> 4) & 1) << 12) | (((t >> 5) & 1) << 13) | (((t >> 6) & 1) << 5)
             | (((t >> 7) & 1) << 6) | (((t >> 8) & 1) << 8);
      int mt = mixA(tp);
#pragma unroll
      for (int f = 0; f < 32; ++f) {
        int fc = ((f & 1) << 9) | (((f >> 1) & 1) << 10) | (((f >> 2) & 1) << 2)
               | (((f >> 3) & 1) << 3) | (((f >> 4) & 1) << 4);
        v[f] = lds[(tp | fc) ^ mt ^ mixA(fc)]; }
      RYT_(csl, 1, 4); RYT_(csl, 2, 3);
      CX_(16, 8); CX_(8, 4); CX_(4, 2); CX_(2, 1);
#pragma unroll
      for (int f = 0; f < 32; ++f) {
        int fc = ((f & 1) << 9) | (((f >> 1) & 1) << 10) | (((f >> 2) & 1) << 2)
               | (((f >> 3) & 1) << 3) | (((f >> 4) & 1) << 4);
        lds[(tp | fc) ^ mt ^ mixA(fc)] = v[f]; } }
    __syncthreads();

    // r3: frag=(E10,E11,E12,E13,E14): RY q5(16); FULL q6(8),q7(4),q8(2),q9(1)
    //     links (15,14)[idx],(14,13),(13,12),(12,11),(11,10)
    { int tp = (t & 31) | (((t >> 5) & 1) << 9) | (((t >> 6) & 1) << 10)
             | (((t >> 7) & 1) << 11) | (((t >> 8) & 1) << 12);
      int mt = mixA(tp);
#pragma unroll
      for (int f = 0; f < 32; ++f) {
        int fc = ((f & 1) << 5) | (((f >> 1) & 1) << 6) | (((f >> 2) & 1) << 7)
               | (((f >> 3) & 1) << 13) | (((f >> 4) & 1) << 8);
        v[f] = lds[(tp | fc) ^ mt ^ mixA(fc)]; }
      RYT_(csl, 16, 5);
      if (FULL) { RYT_(csl, 8, 6); RYT_(csl, 4, 7); RYT_(csl, 2, 8); RYT_(csl, 1, 9); }
      CXI_((t >> 5) & 1, 16); CX_(16, 8); CX_(8, 4); CX_(4, 2); CX_(2, 1);
#pragma unroll
      for (int f = 0; f < 32; ++f) {
        int fc = ((f & 1) << 5) | (((f >> 1) & 1) << 6) | (((f >> 2) & 1) << 7)
               | (((f >> 3) & 1) << 13) | (((f >> 4) & 1) << 8);
        lds[(tp | fc) ^ mt ^ mixA(fc)] = v[f]; } }
    __syncthreads();

    // r4: p=(E6,E13,E7,E8,E9): FULL RY q10(16),q11(8);
    //     links (10,9)[idx t4[6]],(9,8):16->8,(8,7):8->4,(7,6):4->1
    { int tp = ((t & 1) << 8) | (((t >> 1) & 1) << 9) | (((t >> 2) & 1) << 10)
             | (((t >> 3) & 1) << 6) | (((t >> 4) & 1) << 7) | (((t >> 5) & 1) << 2)
             | (((t >> 6) & 1) << 5) | (((t >> 7) & 1) << 3) | (((t >> 8) & 1) << 4);
      int mt = mixA(tp);
#pragma unroll
      for (int p = 0; p < 32; ++p) {
        int fc = ((p & 1) << 0) | (((p >> 1) & 1) << 13) | (((p >> 2) & 1) << 1)
               | (((p >> 3) & 1) << 11) | (((p >> 4) & 1) << 12);
        v[p] = lds[(tp | fc) ^ mt ^ mixA(fc)]; }
      if (FULL) { RYT_(csl, 16, 10); RYT_(csl, 8, 11); }
      CXI_((t >> 6) & 1, 16); CX_(16, 8); CX_(8, 4); CX_(4, 1);
      // store -> P: f4 = b<<18 | G<<12 | j<<9 | t
      int sb = (b << 18) + (G << 12) + t;
#pragma unroll
      for (int j = 0; j < 8; ++j)
        dst[sb + (j << 9)] = make_float4(v[4*j], v[4*j+1], v[4*j+2], v[4*j+3]); }
}

// ---------------- Pass F: P -> Q ----------------
// n: [n0..n4]=(E6,E13,E17,E18,E19) [n5..n10]=(E14,E15,E16,E0,E1,E2)
//    [n11..n13]=(E3,E4,E5)
template <bool LOWRY>
__global__ __launch_bounds__(512, 4) void pass_F(
    const float4* __restrict__ src, float4* __restrict__ dst,
    const float2* __restrict__ cs, int layer)
{
    __shared__ float lds[16384];
    const float2* csl  = cs + layer * 20;         // layer l (low chain / low RY)
    const float2* csl2 = cs + (layer + 1) * 20;   // layer l+1 (hi RY + hi chain)
    int t = threadIdx.x, blk = blockIdx.x;
    int W = blk & 63, b = blk >> 6;
    int Wp = (((W >> 4) & 1) << 3) | (((W >> 5) & 1) << 4) | (((W >> 3) & 1) << 6)
           | ((W & 1) << 9) | (((W >> 1) & 1) << 10) | (((W >> 2) & 1) << 11);
    float v[32];

    // load from P
    { int lb = (((b << 6) | ((t >> 3) & 63)) << 12) + (t & 7) + Wp;
#pragma unroll
      for (int i = 0; i < 8; ++i) {
        float4 w = src[lb + ((i & 1) << 5) + (((i >> 1) & 1) << 7) + (((i >> 2) & 1) << 8)];
        v[i*4+0] = w.x; v[i*4+1] = w.y; v[i*4+2] = w.z; v[i*4+3] = w.w;
      } }
    // r1: m=(E6,E13,E17,E18,E19): RY+1 q0(16),q1(8),q2(4),q6(2); links+1 (19,18),(18,17)
    RYT_(csl2, 16, 0); RYT_(csl2, 8, 1); RYT_(csl2, 4, 2); RYT_(csl2, 2, 6);
    CX_(16, 8); CX_(8, 4);
    { int w1x = (t & 31) ^ (((t >> 5) & 1) << 1) ^ (((t >> 6) & 1) << 2)
              ^ (((t >> 7) & 1) << 3) ^ (((t >> 8) & 1) << 4);
#pragma unroll
      for (int m = 0; m < 32; ++m) lds[(t << 5) | (m ^ w1x)] = v[m]; }
    __syncthreads();

    // r2: frag=(E1,E2,E3,E4,E5): [LOWRY q14(16)..q18(1)]; links_l (6,5)[idx]..(2,1)
    { int tp = (t & 31) | (((t >> 5) & 1) << 8) | (((t >> 6) & 1) << 5)
             | (((t >> 7) & 1) << 6) | (((t >> 8) & 1) << 7);
      int mt = mixF(tp);
#pragma unroll
      for (int f = 0; f < 32; ++f) { int fc = f << 9; v[f] = lds[(tp | fc) ^ mt ^ mixF(fc)]; }
      if (LOWRY) { RYT_(csl, 16, 14); RYT_(csl, 8, 15); RYT_(csl, 4, 16); RYT_(csl, 2, 17); RYT_(csl, 1, 18); }
      CXI_(t & 1, 16); CX_(16, 8); CX_(8, 4); CX_(4, 2); CX_(2, 1);
#pragma unroll
      for (int f = 0; f < 32; ++f) { int fc = f << 9; lds[(tp | fc) ^ mt ^ mixF(fc)] = v[f]; } }
    __syncthreads();

    // r3: p=(E0,E13,E14,E15,E16): [LOWRY q19(1)]; link_l (1,0)[idx t3[3]];
    //     RY+1 q3(16),q4(8),q5(4); links+1 (17,16)[idx t3[6]],(16,15),(15,14),(14,13)
    { int tp = ((t & 1) << 12) | (((t >> 1) & 1) << 13) | (((t >> 2) & 1) << 0)
             | (((t >> 3) & 1) << 9) | (((t >> 4) & 1) << 10) | (((t >> 5) & 1) << 11)
             | (((t >> 6) & 1) << 2) | (((t >> 7) & 1) << 3) | (((t >> 8) & 1) << 4);
      int mt = mixF(tp);
#pragma unroll
      for (int p = 0; p < 32; ++p) {
        int fc = ((p & 1) << 8) | (((p >> 1) & 1) << 1) | (((p >> 2) & 1) << 5)
               | (((p >> 3) & 1) << 6) | (((p >> 4) & 1) << 7);
        v[p] = lds[(tp | fc) ^ mt ^ mixF(fc)]; }
      if (LOWRY) { RYT_(csl, 1, 19); }
      CXI_((t >> 3) & 1, 1);
      RYT_(csl2, 16, 3); RYT_(csl2, 8, 4); RYT_(csl2, 4, 5);
      CXI_((t >> 6) & 1, 16); CX_(16, 8); CX_(8, 4); CX_(4, 2);
      // store -> Q: f4 = blk<<12 | j<<9 | t
      int sb = (blk << 12) + t;
#pragma unroll
      for (int j = 0; j < 8; ++j)
        dst[sb + (j << 9)] = make_float4(v[4*j], v[4*j+1], v[4*j+2], v[4*j+3]); }
}

// ---------------- Pass L: Q -> M (mid) or std+abs (fin) ----------------
// n: [n0..n4]=(E0,E13,E10,E11,E12) [n5..n10]=(E4,E5,E6,E1,E2,E3)
//    [n11..n13]=(E7,E8,E9)
template <bool FIN>
__global__ __launch_bounds__(512, 4) void pass_L(
    const float4* __restrict__ src, float4* __restrict__ dst,
    const float2* __restrict__ cs, int layer)
{
    __shared__ float lds[16384];
    const float2* csl = cs + layer * 20;
    int t = threadIdx.x, blk = blockIdx.x;
    int H = blk & 63, b = blk >> 6;
    int Hp = (((H >> 3) & 7) << 6) | ((H & 7) << 9);
    float v[32];

    // load from Q
    { int rb = (b << 6) | ((t >> 6) & 7);
      int lo = Hp + (t & 63);
#pragma unroll
      for (int i = 0; i < 8; ++i) {
        float4 w = src[((rb | (i << 3)) << 12) + lo];
        v[i*4+0] = w.x; v[i*4+1] = w.y; v[i*4+2] = w.z; v[i*4+3] = w.w;
      } }
    // r1: m=(E0,E13,E10,E11,E12): RY q19(1),q9(4),q8(8),q7(16)
    RYT_(csl, 1, 19); RYT_(csl, 4, 9); RYT_(csl, 8, 8); RYT_(csl, 16, 7);
    { int w1x = (t & 31) ^ (((t >> 5) & 1) << 4) ^ (((t >> 6) & 1) << 2)
              ^ (((t >> 7) & 1) << 3) ^ (((t >> 8) & 1) << 4);
#pragma unroll
      for (int m = 0; m < 32; ++m) lds[(t << 5) | (m ^ w1x)] = v[m]; }
    __syncthreads();

    // r2: frag=(E8,E9,E10,E11,E12): RY q10(2),q11(1);
    //     links (13,12)[idx t2[1]],(12,11),(11,10),(10,9),(9,8)
    { int tp = (t & 3) | (((t >> 2) & 1) << 7) | (((t >> 3) & 1) << 8)
             | (((t >> 4) & 1) << 9) | (((t >> 5) & 1) << 10) | (((t >> 6) & 1) << 5)
             | (((t >> 7) & 1) << 6) | (((t >> 8) & 1) << 11);
      int mt = mixL(tp);
#pragma unroll
      for (int f = 0; f < 32; ++f) {
        int fc = ((f & 1) << 12) | (((f >> 1) & 1) << 13) | (((f >> 2) & 1) << 2)
               | (((f >> 3) & 1) << 3) | (((f >> 4) & 1) << 4);
        v[f] = lds[(tp | fc) ^ mt ^ mixL(fc)]; }
      RYT_(csl, 2, 10); RYT_(csl, 1, 11);
      CXI_((t >> 1) & 1, 16); CX_(16, 8); CX_(8, 4); CX_(4, 2); CX_(2, 1);
#pragma unroll
      for (int f = 0; f < 32; ++f) {
        int fc = ((f & 1) << 12) | (((f >> 1) & 1) << 13) | (((f >> 2) & 1) << 2)
               | (((f >> 3) & 1) << 3) | (((f >> 4) & 1) << 4);
        lds[(tp | fc) ^ mt ^ mixL(fc)] = v[f]; } }
    __syncthreads();

    // r3: frag=(E3,E4,E5,E6,E7): RY q12(16),q13(8),q14(4),q15(2),q16(1);
    //     links (8,7)[idx t3[7]],(7,6),(6,5),(5,4),(4,3)
    { int tp = (t & 31) | (((t >> 5) & 1) << 9) | (((t >> 6) & 1) << 8)
             | (((t >> 7) & 1) << 12) | (((t >> 8) & 1) << 13);
      int mt = mixL(tp);
#pragma unroll
      for (int f = 0; f < 32; ++f) {
        int fc = ((f & 1) << 10) | (((f >> 1) & 1) << 5) | (((f >> 2) & 1) << 6)
               | (((f >> 3) & 1) << 7) | (((f >> 4) & 1) << 11);
        v[f] = lds[(tp | fc) ^ mt ^ mixL(fc)]; }
      RYT_(csl, 16, 12); RYT_(csl, 8, 13); RYT_(csl, 4, 14); RYT_(csl, 2, 15); RYT_(csl, 1, 16);
      CXI_((t >> 7) & 1, 16); CX_(16, 8); CX_(8, 4); CX_(4, 2); CX_(2, 1);
#pragma unroll
      for (int f = 0; f < 32; ++f) {
        int fc = ((f & 1) << 10) | (((f >> 1) & 1) << 5) | (((f >> 2) & 1) << 6)
               | (((f >> 3) & 1) << 7) | (((f >> 4) & 1) << 11);
        lds[(tp | fc) ^ mt ^ mixL(fc)] = v[f]; } }
    __syncthreads();

    // r4: u=(E0,E1,E2,E6,E7): RY q17(4),q18(2); links (3,2)[idx],(2,1),(1,0)
    { int tp;
      if (!FIN)
        tp = ((t & 1) << 2) | (((t >> 1) & 1) << 3) | (((t >> 2) & 1) << 4)
           | (((t >> 3) & 1) << 10) | (((t >> 4) & 1) << 5) | (((t >> 5) & 1) << 6)
           | (((t >> 6) & 1) << 1) | (((t >> 7) & 1) << 12) | (((t >> 8) & 1) << 13);
      else
        tp = ((t & 1) << 10) | (((t >> 1) & 1) << 5) | (((t >> 2) & 1) << 6)
           | (((t >> 3) & 1) << 12) | (((t >> 4) & 1) << 13) | (((t >> 5) & 1) << 2)
           | (((t >> 6) & 1) << 1) | (((t >> 7) & 1) << 3) | (((t >> 8) & 1) << 4);
      int mt = mixL(tp);
#pragma unroll
      for (int u = 0; u < 32; ++u) {
        int fc = ((u & 1) << 0) | (((u >> 1) & 1) << 8) | (((u >> 2) & 1) << 9)
               | (((u >> 3) & 1) << 7) | (((u >> 4) & 1) << 11);
        v[u] = lds[(tp | fc) ^ mt ^ mixL(fc)]; }
      RYT_(csl, 4, 17); RYT_(csl, 2, 18);
      { int e3 = FIN ? (t & 1) : ((t >> 3) & 1);
        CXI_(e3, 4); }
      CX_(4, 2); CX_(2, 1);
      if (!FIN) {
        // store -> M
        int sb = (blk << 12) + (t & 7) + (((t >> 3) & 7) << 6)
               + (((t >> 7) & 3) << 9) + (((t >> 6) & 1) << 11);
#pragma unroll
        for (int g = 0; g < 8; ++g) {
          int bu = ((g >> 2) & 1) | (((g >> 1) & 1) << 1) | ((g & 1) << 2);
          dst[sb + (g << 3)] = make_float4(v[bu], v[bu | 8], v[bu | 16], v[bu | 24]);
        }
      } else {
        // store -> standard, with abs
        int sb = (blk << 12) + ((t & 7) << 1) + (((t >> 3) & 7) << 6)
               + (((t >> 7) & 1) << 9) + (((t >> 8) & 1) << 10) + (((t >> 6) & 1) << 11);
#pragma unroll
        for (int g = 0; g < 8; ++g) {
          int bu = ((g & 1) << 2) | (((g >> 1) & 1) << 3) | (((g >> 2) & 1) << 4);
          dst[sb + (g & 1) + (((g >> 1) & 1) << 4) + (((g >> 2) & 1) << 5)] =
            make_float4(fabsf(v[bu]), fabsf(v[bu | 1]), fabsf(v[bu | 2]), fabsf(v[bu | 3]));
        }
      } }
}

extern "C" void kernel_launch(void* const* d_in, const int* in_sizes, int n_in,
                              void* d_out, int out_size, void* d_ws, size_t ws_size,
                              hipStream_t stream) {
    const float* x     = (const float*)d_in[0];   // (16, 2^20) f32, standard layout
    const float* theta = (const float*)d_in[1];   // (80,) f32
    float2* cs = (float2*)d_ws;                   // 80 (cos,sin) pairs
    float4* wsS = (float4*)((char*)d_ws + 4096);  // 64 MB scratch state
    float4* out = (float4*)d_out;

    cs_kernel<<<1, 128, 0, stream>>>(theta, cs);

    dim3 grid(1024), block(512);
    pass_R<<<grid, block, 0, stream>>>((const float4*)x, out, cs);            // L0 lo-RY
    pass_A<false><<<grid, block, 0, stream>>>(out, wsS, cs, 0);               // L0 hi
    pass_F<false><<<grid, block, 0, stream>>>(wsS, out, cs, 0);               // L0 lo-chain + L1 hi
    pass_L<false><<<grid, block, 0, stream>>>(out, wsS, cs, 1);               // L1 lo
    pass_A<true><<<grid, block, 0, stream>>>(wsS, out, cs, 2);                // L2 hi (full RY)
    pass_F<true><<<grid, block, 0, stream>>>(out, wsS, cs, 2);                // L2 lo + L3 hi
    pass_L<true><<<grid, block, 0, stream>>>(wsS, out, cs, 3);                // L3 lo + abs
}